// Round 6
// baseline (614.299 us; speedup 1.0000x reference)
//
#include <hip/hip_runtime.h>

// LSTM cell fused as one GEMM: Z[B,2048] = [input|h0] (bf16) @ Wint^T (bf16)
// Wint column order c: h_group = c>>6, gate = (c>>4)&3, h_low = c&15.
//
// Round-6 structure: "pin B, stream A" — barrier-free K-loop.
//   BN=64: block's ENTIRE B panel (64 rows x K=1024 bf16 = 128 KiB) staged to
//   LDS once (one __syncthreads), immutable thereafter -> no cross-wave
//   hazards -> ZERO barriers in the K-loop. 512 thr = 8 waves; wave owns a
//   64-row A strip (BM=512), acc[4][4], A-frags loaded DIRECTLY from packed
//   bf16 global (16B/lane, L2-served: XCD-pinned bm => 2 MB A-panel/XCD L2),
//   2-tile-deep per-wave prefetch that no barrier ever drains.
//   B LDS layout: 32 subtiles of [64 rows][32 elems] = r5's measured-0-conflict
//   geometry per subtile; source-swizzled gld_lds + matching read koff.
// B=32768, E=H=512, K=1024, N=2048.

#define BQ 32768
#define HQ 512
#define KK 1024
#define BH (32768 * 512)  // elements per output

typedef __bf16 bf16x8 __attribute__((ext_vector_type(8)));
typedef float f32x4 __attribute__((ext_vector_type(4)));

__device__ __forceinline__ unsigned short f2bf(float f) {
    unsigned int u = __float_as_uint(f);
    unsigned int r = (u + 0x7fffu + ((u >> 16) & 1u)) >> 16;
    return (unsigned short)r;
}

__device__ __forceinline__ void gld_lds16(const unsigned short* g, unsigned short* l) {
    __builtin_amdgcn_global_load_lds(
        (const __attribute__((address_space(1))) void*)g,
        (__attribute__((address_space(3))) void*)l,
        16, 0, 0);
}

// ---- prepass: fp32 -> bf16 packing -----------------------------------------

__global__ __launch_bounds__(256) void pack_X(const float* __restrict__ in,
                                              const float* __restrict__ h0,
                                              unsigned short* __restrict__ Xcat) {
    const int NQ = BQ * HQ / 4;
    int gi = blockIdx.x * 256 + threadIdx.x;
    const float* src;
    size_t dst;
    if (gi < NQ) {
        int e = gi * 4;
        int b = e >> 9, col = e & 511;
        src = in + e;
        dst = (size_t)b * 1024 + col;
    } else {
        int e = (gi - NQ) * 4;
        int b = e >> 9, col = e & 511;
        src = h0 + e;
        dst = (size_t)b * 1024 + 512 + col;
    }
    float4 v = *(const float4*)src;
    ushort4 o;
    o.x = f2bf(v.x); o.y = f2bf(v.y); o.z = f2bf(v.z); o.w = f2bf(v.w);
    *(ushort4*)&Xcat[dst] = o;
}

__global__ __launch_bounds__(256) void pack_W(const float* __restrict__ Wx,
                                              const float* __restrict__ Wh,
                                              const float* __restrict__ bx,
                                              const float* __restrict__ bh,
                                              unsigned short* __restrict__ Wint,
                                              float* __restrict__ biasc) {
    int j = blockIdx.x * 256 + threadIdx.x;
    int c = j >> 8;
    int kc = (j & 255) * 4;
    int gate = (c >> 4) & 3;
    int h = ((c >> 6) << 4) + (c & 15);
    const float* src = (kc < 512)
        ? (Wx + ((size_t)gate * 512 + h) * 512 + kc)
        : (Wh + ((size_t)gate * 512 + h) * 512 + (kc - 512));
    float4 v = *(const float4*)src;
    ushort4 o;
    o.x = f2bf(v.x); o.y = f2bf(v.y); o.z = f2bf(v.z); o.w = f2bf(v.w);
    *(ushort4*)&Wint[(size_t)c * 1024 + kc] = o;
    if ((j & 255) == 0) biasc[c] = bx[gate * 512 + h] + bh[gate * 512 + h];
}

// ---- fused GEMM + LSTM epilogue --------------------------------------------

__global__ __launch_bounds__(512, 2) void lstm_gemm(const unsigned short* __restrict__ Xcat,
                                                    const unsigned short* __restrict__ Wint,
                                                    const float* __restrict__ biasc,
                                                    const float* __restrict__ c0,
                                                    float* __restrict__ out) {
    // 32 K32-subtiles x [64 rows][32 elems] = 128 KiB, immutable after stage
    __shared__ __align__(16) unsigned short ldsB[32 * 2048];

    const int tid = threadIdx.x;
    const int lane = tid & 63;
    const int wave = tid >> 6;     // 0..7: wave owns rows m0+wave*64..+63
    const int quad = lane >> 4;    // 0..3
    const int lrow = lane & 15;    // 0..15

    // Grid 2048 = 64 bm x 32 bn. XCD-pinning: xcd (bid&7) runs a constant bm
    // within each 256-block round -> A-panel (512 rows x 2 KB) L2-resident.
    const int bid = blockIdx.x;
    const int bm = (bid & 7) + ((bid >> 8) << 3);  // 0..63
    const int bn = (bid >> 3) & 31;                // 0..31 (= h_group)
    const int m0 = bm * 512;
    const int n0r = bn * 64;                       // Wint row base

    // ---- stage ENTIRE B panel once: 16 gld_lds/thread, linear dest ----------
    // slot s = j*8 + wave: subtile = s>>2, row-quad = s&3; lane l -> row
    // rq*16 + (l>>2), phys unit l&3 holding source unit (l&3)^((l>>3)&3)
    // (same involution as read-side koff; r5-measured 0 conflicts).
#pragma unroll
    for (int j = 0; j < 16; ++j) {
        const int s = j * 8 + wave;
        const int row = ((s & 3) << 4) + (lane >> 2);
        const int col = ((s >> 2) << 5) + (((lane & 3) ^ ((lane >> 3) & 3)) << 3);
        gld_lds16(Wint + (size_t)(n0r + row) * KK + col, &ldsB[s * 512 + lane * 8]);
    }
    __syncthreads();  // one and only block-wide sync

    // ---- per-wave A pointers (bf16-packed, frag = 16B contiguous) ----------
    const unsigned short* gA0 = Xcat + (size_t)(m0 + wave * 64 +  0 + lrow) * KK + quad * 8;
    const unsigned short* gA1 = Xcat + (size_t)(m0 + wave * 64 + 16 + lrow) * KK + quad * 8;
    const unsigned short* gA2 = Xcat + (size_t)(m0 + wave * 64 + 32 + lrow) * KK + quad * 8;
    const unsigned short* gA3 = Xcat + (size_t)(m0 + wave * 64 + 48 + lrow) * KK + quad * 8;

    // B read offsets within a subtile (r5 pattern): row g*16+lrow, unit
    // quad ^ ((lrow>>1)&3)
    const int koff = (quad ^ ((lrow >> 1) & 3)) * 8;
    const int br0 = (0 * 16 + lrow) * 32 + koff;
    const int br1 = (1 * 16 + lrow) * 32 + koff;
    const int br2 = (2 * 16 + lrow) * 32 + koff;
    const int br3 = (3 * 16 + lrow) * 32 + koff;

    f32x4 acc[4][4];
#pragma unroll
    for (int i = 0; i < 4; i++)
#pragma unroll
        for (int j = 0; j < 4; j++) {
            f32x4 z = {0.f, 0.f, 0.f, 0.f};
            acc[i][j] = z;
        }

    // 2-deep per-wave prefetch; no barrier ever drains these vmcnts.
    bf16x8 preA0 = *(const bf16x8*)(gA0);
    bf16x8 preA1 = *(const bf16x8*)(gA1);
    bf16x8 preA2 = *(const bf16x8*)(gA2);
    bf16x8 preA3 = *(const bf16x8*)(gA3);
    bf16x8 preB0 = *(const bf16x8*)(gA0 + 32);
    bf16x8 preB1 = *(const bf16x8*)(gA1 + 32);
    bf16x8 preB2 = *(const bf16x8*)(gA2 + 32);
    bf16x8 preB3 = *(const bf16x8*)(gA3 + 32);

#define BODY(T, P) do {                                                        \
    bf16x8 a0 = pre##P##0, a1 = pre##P##1, a2 = pre##P##2, a3 = pre##P##3;     \
    if ((T) < 30) {                                                            \
        pre##P##0 = *(const bf16x8*)(gA0 + ((T) + 2) * 32);                    \
        pre##P##1 = *(const bf16x8*)(gA1 + ((T) + 2) * 32);                    \
        pre##P##2 = *(const bf16x8*)(gA2 + ((T) + 2) * 32);                    \
        pre##P##3 = *(const bf16x8*)(gA3 + ((T) + 2) * 32);                    \
    }                                                                          \
    const int tb_ = (T) * 2048;                                                \
    bf16x8 b0 = *(const bf16x8*)&ldsB[tb_ + br0];                              \
    bf16x8 b1 = *(const bf16x8*)&ldsB[tb_ + br1];                              \
    bf16x8 b2 = *(const bf16x8*)&ldsB[tb_ + br2];                              \
    bf16x8 b3 = *(const bf16x8*)&ldsB[tb_ + br3];                              \
    acc[0][0] = __builtin_amdgcn_mfma_f32_16x16x32_bf16(a0, b0, acc[0][0], 0, 0, 0); \
    acc[1][0] = __builtin_amdgcn_mfma_f32_16x16x32_bf16(a1, b0, acc[1][0], 0, 0, 0); \
    acc[2][0] = __builtin_amdgcn_mfma_f32_16x16x32_bf16(a2, b0, acc[2][0], 0, 0, 0); \
    acc[3][0] = __builtin_amdgcn_mfma_f32_16x16x32_bf16(a3, b0, acc[3][0], 0, 0, 0); \
    acc[0][1] = __builtin_amdgcn_mfma_f32_16x16x32_bf16(a0, b1, acc[0][1], 0, 0, 0); \
    acc[1][1] = __builtin_amdgcn_mfma_f32_16x16x32_bf16(a1, b1, acc[1][1], 0, 0, 0); \
    acc[2][1] = __builtin_amdgcn_mfma_f32_16x16x32_bf16(a2, b1, acc[2][1], 0, 0, 0); \
    acc[3][1] = __builtin_amdgcn_mfma_f32_16x16x32_bf16(a3, b1, acc[3][1], 0, 0, 0); \
    acc[0][2] = __builtin_amdgcn_mfma_f32_16x16x32_bf16(a0, b2, acc[0][2], 0, 0, 0); \
    acc[1][2] = __builtin_amdgcn_mfma_f32_16x16x32_bf16(a1, b2, acc[1][2], 0, 0, 0); \
    acc[2][2] = __builtin_amdgcn_mfma_f32_16x16x32_bf16(a2, b2, acc[2][2], 0, 0, 0); \
    acc[3][2] = __builtin_amdgcn_mfma_f32_16x16x32_bf16(a3, b2, acc[3][2], 0, 0, 0); \
    acc[0][3] = __builtin_amdgcn_mfma_f32_16x16x32_bf16(a0, b3, acc[0][3], 0, 0, 0); \
    acc[1][3] = __builtin_amdgcn_mfma_f32_16x16x32_bf16(a1, b3, acc[1][3], 0, 0, 0); \
    acc[2][3] = __builtin_amdgcn_mfma_f32_16x16x32_bf16(a2, b3, acc[2][3], 0, 0, 0); \
    acc[3][3] = __builtin_amdgcn_mfma_f32_16x16x32_bf16(a3, b3, acc[3][3], 0, 0, 0); \
} while (0)

#pragma unroll
    for (int TT = 0; TT < 16; ++TT) {
        BODY(2 * TT, A);
        BODY(2 * TT + 1, B);
    }
#undef BODY

    // epilogue (no sync needed): lane owns gates i,f,o,g at h = bn*16+lrow
    float bi[4];
#pragma unroll
    for (int g = 0; g < 4; g++)
        bi[g] = biasc[n0r + g * 16 + lrow];
    const int h = bn * 16 + lrow;

#pragma unroll
    for (int mi = 0; mi < 4; mi++) {
#pragma unroll
        for (int r = 0; r < 4; r++) {
            int b = m0 + wave * 64 + mi * 16 + quad * 4 + r;
            float zi = acc[mi][0][r] + bi[0];
            float zf = acc[mi][1][r] + bi[1];
            float zo = acc[mi][2][r] + bi[2];
            float zg = acc[mi][3][r] + bi[3];
            float ig = 1.f / (1.f + __expf(-zi));
            float fg = 1.f / (1.f + __expf(-zf));
            float og = 1.f / (1.f + __expf(-zo));
            float gg = 1.f - 2.f / (__expf(2.f * zg) + 1.f);  // tanh, stable
            float c0v = c0[(size_t)b * HQ + h];
            float c1 = fg * c0v + ig * gg;
            float th = 1.f - 2.f / (__expf(2.f * c1) + 1.f);
            out[(size_t)b * HQ + h] = og * th;                 // h1
            out[(size_t)BH + (size_t)b * HQ + h] = c1;         // c1
        }
    }
}

extern "C" void kernel_launch(void* const* d_in, const int* in_sizes, int n_in,
                              void* d_out, int out_size, void* d_ws, size_t ws_size,
                              hipStream_t stream) {
    (void)in_sizes; (void)n_in; (void)out_size; (void)ws_size;
    const float* input = (const float*)d_in[0];
    const float* h0    = (const float*)d_in[1];
    const float* c0    = (const float*)d_in[2];
    const float* Wx    = (const float*)d_in[3];
    const float* bx    = (const float*)d_in[4];
    const float* Wh    = (const float*)d_in[5];
    const float* bh    = (const float*)d_in[6];
    float* out = (float*)d_out;

    char* ws = (char*)d_ws;
    unsigned short* Xcat = (unsigned short*)ws;                      // 64 MiB
    unsigned short* Wint = (unsigned short*)(ws + (size_t)67108864); // 4 MiB
    float* biasc = (float*)(ws + (size_t)71303168);                  // 8 KiB

    pack_X<<<32768, 256, 0, stream>>>(input, h0, Xcat);
    pack_W<<<2048, 256, 0, stream>>>(Wx, Wh, bx, bh, Wint, biasc);
    lstm_gemm<<<2048, 512, 0, stream>>>(Xcat, Wint, biasc, c0, out);
}

// Round 7
// 510.005 us; speedup vs baseline: 1.2045x; 1.2045x over previous
//
#include <hip/hip_runtime.h>

// LSTM cell fused as one GEMM: Z[B,2048] = [input|h0] (bf16) @ Wint^T (bf16)
// Wint column order c: h_group = c>>6, gate = (c>>4)&3, h_low = c&15.
//
// Round-7: r6's "pin B, stream A" barrier-free K-loop + FRAGMENT-MAJOR A.
//   pack_X stores Xcat in MFMA fragment order: subtile (mtile 16 rows x
//   ktile 32 cols) = 512 contiguous ushorts, element (quad*16+lrow)*8+e.
//   => wave A-frag load = base + lane*16: ONE coalesced 1KB dwordx4 burst
//   (r6's fatal flaw was 64 scattered 16B transactions per frag).
//   B: entire 64-row x K panel (128 KiB) staged to LDS once, immutable ->
//   zero barriers in K-loop; r6-verified swizzle (0 conflicts).
//   A prefetch 3 K-tiles deep per wave; XCD-pinned bm => A-panel (1 MB)
//   L2-resident with 32x reuse.
// B=32768, E=H=512, K=1024, N=2048.

#define BQ 32768
#define HQ 512
#define KK 1024
#define BH (32768 * 512)  // elements per output

typedef __bf16 bf16x8 __attribute__((ext_vector_type(8)));
typedef float f32x4 __attribute__((ext_vector_type(4)));

__device__ __forceinline__ unsigned short f2bf(float f) {
    unsigned int u = __float_as_uint(f);
    unsigned int r = (u + 0x7fffu + ((u >> 16) & 1u)) >> 16;
    return (unsigned short)r;
}

__device__ __forceinline__ void gld_lds16(const unsigned short* g, unsigned short* l) {
    __builtin_amdgcn_global_load_lds(
        (const __attribute__((address_space(1))) void*)g,
        (__attribute__((address_space(3))) void*)l,
        16, 0, 0);
}

// ---- prepass: fp32 -> bf16 packing, fragment-major -------------------------

__global__ __launch_bounds__(256) void pack_X(const float* __restrict__ in,
                                              const float* __restrict__ h0,
                                              unsigned short* __restrict__ Xcat) {
    const int NQ = BQ * HQ / 4;
    int gi = blockIdx.x * 256 + threadIdx.x;
    const float* src;
    int b, ccat;
    if (gi < NQ) {
        int e = gi * 4;
        b = e >> 9;
        ccat = e & 511;
        src = in + e;
    } else {
        int e = (gi - NQ) * 4;
        b = e >> 9;
        ccat = (e & 511) + 512;
        src = h0 + e;
    }
    const int mtile = b >> 4, lrow = b & 15;
    const int kt = ccat >> 5, kin = ccat & 31;
    const int quad = kin >> 3, e0 = kin & 7;
    size_t dst = ((size_t)mtile * 32 + kt) * 512 + (quad * 16 + lrow) * 8 + e0;
    float4 v = *(const float4*)src;
    ushort4 o;
    o.x = f2bf(v.x); o.y = f2bf(v.y); o.z = f2bf(v.z); o.w = f2bf(v.w);
    *(ushort4*)&Xcat[dst] = o;
}

__global__ __launch_bounds__(256) void pack_W(const float* __restrict__ Wx,
                                              const float* __restrict__ Wh,
                                              const float* __restrict__ bx,
                                              const float* __restrict__ bh,
                                              unsigned short* __restrict__ Wint,
                                              float* __restrict__ biasc) {
    int j = blockIdx.x * 256 + threadIdx.x;
    int c = j >> 8;
    int kc = (j & 255) * 4;
    int gate = (c >> 4) & 3;
    int h = ((c >> 6) << 4) + (c & 15);
    const float* src = (kc < 512)
        ? (Wx + ((size_t)gate * 512 + h) * 512 + kc)
        : (Wh + ((size_t)gate * 512 + h) * 512 + (kc - 512));
    float4 v = *(const float4*)src;
    ushort4 o;
    o.x = f2bf(v.x); o.y = f2bf(v.y); o.z = f2bf(v.z); o.w = f2bf(v.w);
    *(ushort4*)&Wint[(size_t)c * 1024 + kc] = o;
    if ((j & 255) == 0) biasc[c] = bx[gate * 512 + h] + bh[gate * 512 + h];
}

// ---- fused GEMM + LSTM epilogue --------------------------------------------

__global__ __launch_bounds__(512, 2) void lstm_gemm(const unsigned short* __restrict__ Xcat,
                                                    const unsigned short* __restrict__ Wint,
                                                    const float* __restrict__ biasc,
                                                    const float* __restrict__ c0,
                                                    float* __restrict__ out) {
    // 32 K32-subtiles x [64 rows][32 elems] = 128 KiB, immutable after stage
    __shared__ __align__(16) unsigned short ldsB[32 * 2048];

    const int tid = threadIdx.x;
    const int lane = tid & 63;
    const int wave = tid >> 6;     // 0..7: wave owns rows m0+wave*64..+63
    const int quad = lane >> 4;    // 0..3
    const int lrow = lane & 15;    // 0..15

    // Grid 2048: xcd = bid&7 owns bm in [xcd*8, xcd*8+8); bn = (bid>>3)&31.
    // Co-resident blocks on an XCD share one 1 MB A-panel (L2-resident, 32x).
    const int bid = blockIdx.x;
    const int idx = bid >> 3;
    const int bn = idx & 31;                    // 0..31 (= h_group)
    const int bm = (bid & 7) * 8 + (idx >> 5);  // 0..63
    const int m0 = bm * 512;
    const int n0r = bn * 64;                    // Wint row base

    // ---- stage ENTIRE B panel once (r6-verified, 0 conflicts) --------------
#pragma unroll
    for (int j = 0; j < 16; ++j) {
        const int s = j * 8 + wave;
        const int row = ((s & 3) << 4) + (lane >> 2);
        const int col = ((s >> 2) << 5) + (((lane & 3) ^ ((lane >> 3) & 3)) << 3);
        gld_lds16(Wint + (size_t)(n0r + row) * KK + col, &ldsB[s * 512 + lane * 8]);
    }
    __syncthreads();  // one and only block-wide sync

    // ---- fragment-major A pointers: frag(mtile,T) at (mtile*32+T)*512 + lane*8
    const int mt0 = bm * 32 + wave * 4;   // wave's first mtile
    const unsigned short* gF0 = Xcat + ((size_t)(mt0 + 0) * 32) * 512 + lane * 8;
    const unsigned short* gF1 = Xcat + ((size_t)(mt0 + 1) * 32) * 512 + lane * 8;
    const unsigned short* gF2 = Xcat + ((size_t)(mt0 + 2) * 32) * 512 + lane * 8;
    const unsigned short* gF3 = Xcat + ((size_t)(mt0 + 3) * 32) * 512 + lane * 8;

    // B read offsets within a subtile (verified swizzle)
    const int koff = (quad ^ ((lrow >> 1) & 3)) * 8;
    const int br0 = (0 * 16 + lrow) * 32 + koff;
    const int br1 = (1 * 16 + lrow) * 32 + koff;
    const int br2 = (2 * 16 + lrow) * 32 + koff;
    const int br3 = (3 * 16 + lrow) * 32 + koff;

    f32x4 acc[4][4];
#pragma unroll
    for (int i = 0; i < 4; i++)
#pragma unroll
        for (int j = 0; j < 4; j++) {
            f32x4 z = {0.f, 0.f, 0.f, 0.f};
            acc[i][j] = z;
        }

    // 3-deep per-wave A prefetch; no barrier ever drains these vmcnts.
    bf16x8 pA0 = *(const bf16x8*)(gF0 +   0), pA1 = *(const bf16x8*)(gF1 +   0),
           pA2 = *(const bf16x8*)(gF2 +   0), pA3 = *(const bf16x8*)(gF3 +   0);
    bf16x8 pB0 = *(const bf16x8*)(gF0 + 512), pB1 = *(const bf16x8*)(gF1 + 512),
           pB2 = *(const bf16x8*)(gF2 + 512), pB3 = *(const bf16x8*)(gF3 + 512);
    bf16x8 pC0 = *(const bf16x8*)(gF0 + 1024), pC1 = *(const bf16x8*)(gF1 + 1024),
           pC2 = *(const bf16x8*)(gF2 + 1024), pC3 = *(const bf16x8*)(gF3 + 1024);

#define BODY(T, P, PF) do {                                                    \
    bf16x8 a0 = p##P##0, a1 = p##P##1, a2 = p##P##2, a3 = p##P##3;             \
    if (PF) {                                                                  \
        const int o_ = ((T) + 3) * 512;                                        \
        p##P##0 = *(const bf16x8*)(gF0 + o_);                                  \
        p##P##1 = *(const bf16x8*)(gF1 + o_);                                  \
        p##P##2 = *(const bf16x8*)(gF2 + o_);                                  \
        p##P##3 = *(const bf16x8*)(gF3 + o_);                                  \
    }                                                                          \
    const int tb_ = (T) * 2048;                                                \
    bf16x8 b0 = *(const bf16x8*)&ldsB[tb_ + br0];                              \
    bf16x8 b1 = *(const bf16x8*)&ldsB[tb_ + br1];                              \
    bf16x8 b2 = *(const bf16x8*)&ldsB[tb_ + br2];                              \
    bf16x8 b3 = *(const bf16x8*)&ldsB[tb_ + br3];                              \
    acc[0][0] = __builtin_amdgcn_mfma_f32_16x16x32_bf16(a0, b0, acc[0][0], 0, 0, 0); \
    acc[1][0] = __builtin_amdgcn_mfma_f32_16x16x32_bf16(a1, b0, acc[1][0], 0, 0, 0); \
    acc[2][0] = __builtin_amdgcn_mfma_f32_16x16x32_bf16(a2, b0, acc[2][0], 0, 0, 0); \
    acc[3][0] = __builtin_amdgcn_mfma_f32_16x16x32_bf16(a3, b0, acc[3][0], 0, 0, 0); \
    acc[0][1] = __builtin_amdgcn_mfma_f32_16x16x32_bf16(a0, b1, acc[0][1], 0, 0, 0); \
    acc[1][1] = __builtin_amdgcn_mfma_f32_16x16x32_bf16(a1, b1, acc[1][1], 0, 0, 0); \
    acc[2][1] = __builtin_amdgcn_mfma_f32_16x16x32_bf16(a2, b1, acc[2][1], 0, 0, 0); \
    acc[3][1] = __builtin_amdgcn_mfma_f32_16x16x32_bf16(a3, b1, acc[3][1], 0, 0, 0); \
    acc[0][2] = __builtin_amdgcn_mfma_f32_16x16x32_bf16(a0, b2, acc[0][2], 0, 0, 0); \
    acc[1][2] = __builtin_amdgcn_mfma_f32_16x16x32_bf16(a1, b2, acc[1][2], 0, 0, 0); \
    acc[2][2] = __builtin_amdgcn_mfma_f32_16x16x32_bf16(a2, b2, acc[2][2], 0, 0, 0); \
    acc[3][2] = __builtin_amdgcn_mfma_f32_16x16x32_bf16(a3, b2, acc[3][2], 0, 0, 0); \
    acc[0][3] = __builtin_amdgcn_mfma_f32_16x16x32_bf16(a0, b3, acc[0][3], 0, 0, 0); \
    acc[1][3] = __builtin_amdgcn_mfma_f32_16x16x32_bf16(a1, b3, acc[1][3], 0, 0, 0); \
    acc[2][3] = __builtin_amdgcn_mfma_f32_16x16x32_bf16(a2, b3, acc[2][3], 0, 0, 0); \
    acc[3][3] = __builtin_amdgcn_mfma_f32_16x16x32_bf16(a3, b3, acc[3][3], 0, 0, 0); \
} while (0)

    for (int TT = 0; TT < 27; TT += 3) {
        BODY(TT + 0, A, 1);
        BODY(TT + 1, B, 1);
        BODY(TT + 2, C, 1);
    }
    BODY(27, A, 1);   // prefetches T=30
    BODY(28, B, 1);   // prefetches T=31
    BODY(29, C, 0);
    BODY(30, A, 0);
    BODY(31, B, 0);
#undef BODY

    // epilogue (no sync needed): lane owns gates i,f,o,g at h = bn*16+lrow
    float bi[4];
#pragma unroll
    for (int g = 0; g < 4; g++)
        bi[g] = biasc[n0r + g * 16 + lrow];
    const int h = bn * 16 + lrow;

#pragma unroll
    for (int mi = 0; mi < 4; mi++) {
#pragma unroll
        for (int r = 0; r < 4; r++) {
            int b = m0 + wave * 64 + mi * 16 + quad * 4 + r;
            float zi = acc[mi][0][r] + bi[0];
            float zf = acc[mi][1][r] + bi[1];
            float zo = acc[mi][2][r] + bi[2];
            float zg = acc[mi][3][r] + bi[3];
            float ig = 1.f / (1.f + __expf(-zi));
            float fg = 1.f / (1.f + __expf(-zf));
            float og = 1.f / (1.f + __expf(-zo));
            float gg = 1.f - 2.f / (__expf(2.f * zg) + 1.f);  // tanh, stable
            float c0v = c0[(size_t)b * HQ + h];
            float c1 = fg * c0v + ig * gg;
            float th = 1.f - 2.f / (__expf(2.f * c1) + 1.f);
            out[(size_t)b * HQ + h] = og * th;                 // h1
            out[(size_t)BH + (size_t)b * HQ + h] = c1;         // c1
        }
    }
}

extern "C" void kernel_launch(void* const* d_in, const int* in_sizes, int n_in,
                              void* d_out, int out_size, void* d_ws, size_t ws_size,
                              hipStream_t stream) {
    (void)in_sizes; (void)n_in; (void)out_size; (void)ws_size;
    const float* input = (const float*)d_in[0];
    const float* h0    = (const float*)d_in[1];
    const float* c0    = (const float*)d_in[2];
    const float* Wx    = (const float*)d_in[3];
    const float* bx    = (const float*)d_in[4];
    const float* Wh    = (const float*)d_in[5];
    const float* bh    = (const float*)d_in[6];
    float* out = (float*)d_out;

    char* ws = (char*)d_ws;
    unsigned short* Xcat = (unsigned short*)ws;                      // 64 MiB
    unsigned short* Wint = (unsigned short*)(ws + (size_t)67108864); // 4 MiB
    float* biasc = (float*)(ws + (size_t)71303168);                  // 8 KiB

    pack_X<<<32768, 256, 0, stream>>>(input, h0, Xcat);
    pack_W<<<2048, 256, 0, stream>>>(Wx, Wh, bx, bh, Wint, biasc);
    lstm_gemm<<<2048, 512, 0, stream>>>(Xcat, Wint, biasc, c0, out);
}